// Round 2
// baseline (36340.005 us; speedup 1.0000x reference)
//
#include <hip/hip_runtime.h>
#include <math.h>

#define HD 512
#define TT 512
#define NB 128
#define G3 1536
#define NBLK 256          // persistent blocks = CU count
#define NU 16             // hidden units per block
#define NBB 16            // batches per block
#define NTHR 512
#define HBUF_N (NB * HD)  // floats per h buffer

__global__ void init_sync(int* s) {
    if (threadIdx.x == 0) { s[0] = 0; s[1] = 0; }
}

__device__ __forceinline__ float sigm(float v) { return 1.0f / (1.0f + __expf(-v)); }

// Device-wide barrier: cumulative count + monotonic sense, agent-scope.
__device__ __forceinline__ void gbar(int* cnt, int* sns, int p) {
    __syncthreads();   // all waves drain their global stores (vmcnt 0) before arrival
    if (threadIdx.x == 0) {
        __threadfence();  // L2 writeback for cross-XCD visibility
        const int old = __hip_atomic_fetch_add(cnt, 1, __ATOMIC_ACQ_REL, __HIP_MEMORY_SCOPE_AGENT);
        if (old == NBLK * p - 1) {
            __hip_atomic_store(sns, p, __ATOMIC_RELEASE, __HIP_MEMORY_SCOPE_AGENT);
        } else {
            while (__hip_atomic_load(sns, __ATOMIC_ACQUIRE, __HIP_MEMORY_SCOPE_AGENT) < p)
                __builtin_amdgcn_s_sleep(1);
        }
        __threadfence();  // invalidate caches before reading others' h
    }
    __syncthreads();
}

// One GRU step for this block's (16 units x 16 batches) slice.
// W: float4[3][4] per-thread VGPR-resident weight fragment.
// Thread map: u = tid>>5 (unit), kq = tid&31 (k-lane). Thread covers
// k in {i*128 + 4*kq .. +4 : i<4}; butterfly over kq completes the dot.
#define STEP_GEMM(W, WIR, WIZ, WIN, CR, CZ, BIN, BHN, WBUF)                      \
  {                                                                              \
    float acc[3][16];                                                            \
    _Pragma("unroll") for (int g = 0; g < 3; ++g)                                \
      _Pragma("unroll") for (int b = 0; b < 16; ++b) acc[g][b] = 0.f;            \
    _Pragma("unroll") for (int i = 0; i < 4; ++i) {                              \
      _Pragma("unroll") for (int b = 0; b < 16; ++b) {                           \
        const float4 hb = *(const float4*)&hs[b][i * 128 + 4 * kq];              \
        _Pragma("unroll") for (int g = 0; g < 3; ++g) {                          \
          acc[g][b] = fmaf(W[g][i].x, hb.x, acc[g][b]);                          \
          acc[g][b] = fmaf(W[g][i].y, hb.y, acc[g][b]);                          \
          acc[g][b] = fmaf(W[g][i].z, hb.z, acc[g][b]);                          \
          acc[g][b] = fmaf(W[g][i].w, hb.w, acc[g][b]);                          \
        }                                                                        \
      }                                                                          \
    }                                                                            \
    _Pragma("unroll") for (int g = 0; g < 3; ++g)                                \
      _Pragma("unroll") for (int b = 0; b < 16; ++b) {                           \
        float v = acc[g][b];                                                     \
        v += __shfl_xor(v, 1);  v += __shfl_xor(v, 2);  v += __shfl_xor(v, 4);   \
        v += __shfl_xor(v, 8);  v += __shfl_xor(v, 16);                          \
        acc[g][b] = v;                                                           \
      }                                                                          \
    if (kq < NBB) {                                                              \
      float ar = 0.f, az = 0.f, an = 0.f;                                        \
      _Pragma("unroll") for (int b = 0; b < 16; ++b) {                           \
        if (kq == b) { ar = acc[0][b]; az = acc[1][b]; an = acc[2][b]; }         \
      }                                                                          \
      const float xv = xin_s[kq];                                                \
      const float r = sigm(fmaf(xv, WIR, CR) + ar);                              \
      const float z = sigm(fmaf(xv, WIZ, CZ) + az);                              \
      const float n = tanhf(fmaf(xv, WIN, BIN) + r * (an + BHN));                \
      const float hp = hs[kq][u0 + u];                                           \
      (WBUF)[(b0 + kq) * HD + u0 + u] = fmaf(z, hp - n, n);                      \
    }                                                                            \
  }

__global__ __launch_bounds__(NTHR, 2) void gru_persist(
    const float* __restrict__ x,
    const float* __restrict__ eWi, const float* __restrict__ eWh,
    const float* __restrict__ ebi, const float* __restrict__ ebh,
    const float* __restrict__ dWi, const float* __restrict__ dWh,
    const float* __restrict__ dbi, const float* __restrict__ dbh,
    const float* __restrict__ linW, const float* __restrict__ linb,
    float* __restrict__ hbuf, int* __restrict__ sync_w,
    float* __restrict__ out)
{
    const int blk = blockIdx.x;
    const int bg  = blk >> 5;     // 0..7  batch group
    const int us  = blk & 31;     // 0..31 unit slice
    const int b0  = bg * NBB;
    const int u0  = us * NU;
    const int tid = threadIdx.x;
    const int u   = tid >> 5;     // 0..15 unit (also y-batch index)
    const int kq  = tid & 31;     // 0..31 k lane

    __shared__ float hs[NBB][HD + 4];   // +4 pad: conflict-free y-dot rows
    __shared__ float xin_s[NBB];        // x_t (enc) or y_t (dec)
    __shared__ float lin_s[HD];

    // ---- weights resident in VGPRs (enc + dec), loaded once ----
    float4 wE[3][4], wD[3][4];
    const int ur = u0 + u;
    #pragma unroll
    for (int g = 0; g < 3; ++g) {
        const int row = g * HD + ur;
        #pragma unroll
        for (int i = 0; i < 4; ++i) {
            wE[g][i] = *(const float4*)&eWh[row * HD + i * 128 + 4 * kq];
            wD[g][i] = *(const float4*)&dWh[row * HD + i * 128 + 4 * kq];
        }
    }
    const float e_wi_r = eWi[ur], e_wi_z = eWi[HD + ur], e_wi_n = eWi[2 * HD + ur];
    const float e_c_r  = ebi[ur] + ebh[ur];
    const float e_c_z  = ebi[HD + ur] + ebh[HD + ur];
    const float e_bi_n = ebi[2 * HD + ur], e_bh_n = ebh[2 * HD + ur];
    const float d_wi_r = dWi[ur], d_wi_z = dWi[HD + ur], d_wi_n = dWi[2 * HD + ur];
    const float d_c_r  = dbi[ur] + dbh[ur];
    const float d_c_z  = dbi[HD + ur] + dbh[HD + ur];
    const float d_bi_n = dbi[2 * HD + ur], d_bh_n = dbh[2 * HD + ur];
    lin_s[tid] = linW[tid];
    const float lb = linb[0];

    int phase = 0;

    // ---------------- encoder: 512 steps ----------------
    for (int s = 0; s < TT; ++s) {
        if (s == 0) {
            for (int i = tid; i < NBB * HD; i += NTHR) hs[i >> 9][i & (HD - 1)] = 0.f;
        } else {
            const float* src = hbuf + ((s + 1) & 1) * HBUF_N + b0 * HD;
            for (int i = tid; i < NBB * 128; i += NTHR) {
                const int b = i >> 7, r4 = i & 127;
                *(float4*)&hs[b][4 * r4] = *(const float4*)&src[b * HD + 4 * r4];
            }
        }
        if (tid < NBB) xin_s[tid] = x[(b0 + tid) * TT + s];
        __syncthreads();
        float* wb = hbuf + (s & 1) * HBUF_N;
        STEP_GEMM(wE, e_wi_r, e_wi_z, e_wi_n, e_c_r, e_c_z, e_bi_n, e_bh_n, wb);
        gbar(sync_w, sync_w + 1, ++phase);
    }

    // ---------------- decoder: 512 steps + final emit ----------------
    for (int s = 0; s <= TT; ++s) {
        const float* src = hbuf + ((s + 1) & 1) * HBUF_N + b0 * HD;
        for (int i = tid; i < NBB * 128; i += NTHR) {
            const int b = i >> 7, r4 = i & 127;
            *(float4*)&hs[b][4 * r4] = *(const float4*)&src[b * HD + 4 * r4];
        }
        __syncthreads();
        // y[b] = hs[b] . linW + lb   (b = u field, k-slice = kq), redundant per block
        {
            float p = 0.f;
            #pragma unroll
            for (int i = 0; i < 4; ++i) {
                const float4 hv = *(const float4*)&hs[u][i * 128 + 4 * kq];
                const float4 lv = *(const float4*)&lin_s[i * 128 + 4 * kq];
                p = fmaf(hv.x, lv.x, p); p = fmaf(hv.y, lv.y, p);
                p = fmaf(hv.z, lv.z, p); p = fmaf(hv.w, lv.w, p);
            }
            p += __shfl_xor(p, 1); p += __shfl_xor(p, 2); p += __shfl_xor(p, 4);
            p += __shfl_xor(p, 8); p += __shfl_xor(p, 16);
            if (kq == 0) xin_s[u] = p + lb;
        }
        __syncthreads();
        if (s >= 1 && us == 0 && tid < NBB)
            out[(b0 + tid) * TT + (TT - s)] = xin_s[tid];
        if (s < TT) {
            float* wb = hbuf + (s & 1) * HBUF_N;
            STEP_GEMM(wD, d_wi_r, d_wi_z, d_wi_n, d_c_r, d_c_z, d_bi_n, d_bh_n, wb);
            gbar(sync_w, sync_w + 1, ++phase);
        }
    }
}

extern "C" void kernel_launch(void* const* d_in, const int* in_sizes, int n_in,
                              void* d_out, int out_size, void* d_ws, size_t ws_size,
                              hipStream_t stream) {
    const float* x    = (const float*)d_in[0];
    const float* eWi  = (const float*)d_in[1];
    const float* eWh  = (const float*)d_in[2];
    const float* ebi  = (const float*)d_in[3];
    const float* ebh  = (const float*)d_in[4];
    const float* dWi  = (const float*)d_in[5];
    const float* dWh  = (const float*)d_in[6];
    const float* dbi  = (const float*)d_in[7];
    const float* dbh  = (const float*)d_in[8];
    const float* linW = (const float*)d_in[9];
    const float* linb = (const float*)d_in[10];
    float* out  = (float*)d_out;

    float* hbuf = (float*)d_ws;                  // 2 * 128 * 512 fp32 = 512 KB
    int*   sync_w = (int*)(hbuf + 2 * HBUF_N);   // {count, sense}

    init_sync<<<1, 64, 0, stream>>>(sync_w);
    gru_persist<<<dim3(NBLK), dim3(NTHR), 0, stream>>>(
        x, eWi, eWh, ebi, ebh, dWi, dWh, dbi, dbh, linW, linb,
        hbuf, sync_w, out);
}

// Round 3
// 8524.582 us; speedup vs baseline: 4.2630x; 4.2630x over previous
//
#include <hip/hip_runtime.h>
#include <math.h>

#define HD 512
#define TT 512
#define NB 128
#define NBLK 256          // 8 batch-groups x 32 unit-slices
#define NGRP 8
#define GBLK 32           // blocks per barrier group
#define NU 16             // units per block
#define NBB 16            // batches per block
#define NTHR 512
#define HBUF_N (NB * HD)  // floats per h buffer (256 KB)

__global__ void init_sync(int* s) {
    if (threadIdx.x < NGRP * 64) s[threadIdx.x] = 0;
}

__device__ __forceinline__ float sigm(float v) { return 1.0f / (1.0f + __expf(-v)); }

// ---- coherent (LLC) h exchange: relaxed system-scope atomics, NO fences ----
#define H_LOAD(p)    __hip_atomic_load((p), __ATOMIC_RELAXED, __HIP_MEMORY_SCOPE_SYSTEM)
#define H_STORE(p,v) __hip_atomic_store((p), (v), __ATOMIC_RELAXED, __HIP_MEMORY_SCOPE_SYSTEM)

// Stage 16 batches x 512 h (32 KB, contiguous) from hbuf parity PAR into hs.
#define STAGE(PAR)                                                              \
  { const float* srcp = hbuf + (PAR) * HBUF_N + (size_t)b0 * HD;                \
    float vv[16];                                                               \
    _Pragma("unroll") for (int i = 0; i < 16; ++i)                              \
      vv[i] = H_LOAD(srcp + i * NTHR + tid);                                    \
    _Pragma("unroll") for (int i = 0; i < 16; ++i) hs[i][tid] = vv[i]; }

// Group barrier: cumulative per-group counter, relaxed add + relaxed spin.
// Ordering: __syncthreads() drains each wave's vmcnt(0) (coherent stores are
// LLC-acked) before the add; spinners' subsequent coherent loads read LLC.
#define GBAR()                                                                  \
  { __syncthreads();                                                            \
    target += GBLK;                                                             \
    if (tid == 0) {                                                             \
      __hip_atomic_fetch_add(cnt, 1, __ATOMIC_RELAXED, __HIP_MEMORY_SCOPE_SYSTEM); \
      while (__hip_atomic_load(cnt, __ATOMIC_RELAXED, __HIP_MEMORY_SCOPE_SYSTEM)   \
             < target) __builtin_amdgcn_s_sleep(1);                             \
    }                                                                           \
    __syncthreads(); }

// One GRU step for the (16u x 16b) slice. wW: VGPR-resident weight fragment,
// wW[g][i] = Wh[g*512+ur][4*kq+128*i .. +3]. Butterfly allreduce over kq.
#define STEP(WIR, WIZ, WIN, CR, CZ, BIN, BHN, WBUF)                             \
  { float acc[3][NBB];                                                          \
    _Pragma("unroll") for (int g = 0; g < 3; ++g)                               \
      _Pragma("unroll") for (int b = 0; b < NBB; ++b) acc[g][b] = 0.f;          \
    _Pragma("unroll") for (int i = 0; i < 4; ++i) {                             \
      _Pragma("unroll") for (int b = 0; b < NBB; ++b) {                         \
        const float4 hb = *(const float4*)&hs[b][4 * kq + 128 * i];             \
        acc[0][b] = fmaf(wW[0][i].x, hb.x, acc[0][b]);                          \
        acc[1][b] = fmaf(wW[1][i].x, hb.x, acc[1][b]);                          \
        acc[2][b] = fmaf(wW[2][i].x, hb.x, acc[2][b]);                          \
        acc[0][b] = fmaf(wW[0][i].y, hb.y, acc[0][b]);                          \
        acc[1][b] = fmaf(wW[1][i].y, hb.y, acc[1][b]);                          \
        acc[2][b] = fmaf(wW[2][i].y, hb.y, acc[2][b]);                          \
        acc[0][b] = fmaf(wW[0][i].z, hb.z, acc[0][b]);                          \
        acc[1][b] = fmaf(wW[1][i].z, hb.z, acc[1][b]);                          \
        acc[2][b] = fmaf(wW[2][i].z, hb.z, acc[2][b]);                          \
        acc[0][b] = fmaf(wW[0][i].w, hb.w, acc[0][b]);                          \
        acc[1][b] = fmaf(wW[1][i].w, hb.w, acc[1][b]);                          \
        acc[2][b] = fmaf(wW[2][i].w, hb.w, acc[2][b]);                          \
      } }                                                                       \
    _Pragma("unroll") for (int g = 0; g < 3; ++g)                               \
      _Pragma("unroll") for (int b = 0; b < NBB; ++b) {                         \
        float v = acc[g][b];                                                    \
        v += __shfl_xor(v, 1);  v += __shfl_xor(v, 2);  v += __shfl_xor(v, 4);  \
        v += __shfl_xor(v, 8);  v += __shfl_xor(v, 16);                         \
        acc[g][b] = v;                                                          \
      }                                                                         \
    if (kq < NBB) {                                                             \
      float ar = 0.f, az = 0.f, an = 0.f;                                       \
      _Pragma("unroll") for (int b = 0; b < NBB; ++b)                           \
        if (kq == b) { ar = acc[0][b]; az = acc[1][b]; an = acc[2][b]; }        \
      const float xv = xin_s[kq];                                               \
      const float r = sigm(fmaf(xv, WIR, CR) + ar);                             \
      const float z = sigm(fmaf(xv, WIZ, CZ) + az);                             \
      const float n = tanhf(fmaf(xv, WIN, BIN) + r * (an + BHN));               \
      const float hp = hs[kq][ur];                                              \
      H_STORE((WBUF) + (size_t)(b0 + kq) * HD + ur, fmaf(z, hp - n, n));        \
    } }

__global__ __launch_bounds__(NTHR, 2) void gru_persist(
    const float* __restrict__ x,
    const float* __restrict__ eWi, const float* __restrict__ eWh,
    const float* __restrict__ ebi, const float* __restrict__ ebh,
    const float* __restrict__ dWi, const float* __restrict__ dWh,
    const float* __restrict__ dbi, const float* __restrict__ dbh,
    const float* __restrict__ linW, const float* __restrict__ linb,
    float* __restrict__ hbuf, int* __restrict__ sync_w,
    float* __restrict__ out)
{
    const int blk = blockIdx.x;
    const int bg  = blk >> 5;      // batch group 0..7
    const int us  = blk & 31;      // unit slice 0..31
    const int b0  = bg * NBB;
    const int u0  = us * NU;
    const int tid = threadIdx.x;
    const int u   = tid >> 5;      // 0..15 unit (y-dot: batch slot)
    const int kq  = tid & 31;      // k lane
    const int ur  = u0 + u;

    __shared__ float hs[NBB][HD + 4];  // staged h, 16 rows x 512 (pad 4)
    __shared__ float xin_s[NBB];       // x_t (enc) / y_t (dec)
    __shared__ float lin_s[HD];

    int* cnt = sync_w + bg * 64;       // 256B-spaced group counters
    int  target = 0;

    // encoder Wh fragment -> VGPRs (decoder loaded after encoder: reg pressure)
    float4 wW[3][4];
    #pragma unroll
    for (int g = 0; g < 3; ++g) {
        const size_t row = (size_t)(g * HD + ur) * HD;
        #pragma unroll
        for (int i = 0; i < 4; ++i)
            wW[g][i] = *(const float4*)&eWh[row + i * 128 + 4 * kq];
    }
    float wi_r = eWi[ur], wi_z = eWi[HD + ur], wi_n = eWi[2 * HD + ur];
    float c_r  = ebi[ur] + ebh[ur];
    float c_z  = ebi[HD + ur] + ebh[HD + ur];
    float bi_n = ebi[2 * HD + ur], bh_n = ebh[2 * HD + ur];
    lin_s[tid] = linW[tid];
    const float lb = linb[0];

    // ---------------- encoder ----------------
    for (int s = 0; s < TT; ++s) {
        if (s == 0) {
            #pragma unroll
            for (int i = 0; i < 16; ++i) hs[i][tid] = 0.f;
        } else {
            STAGE((s + 1) & 1);
        }
        if (tid < NBB) xin_s[tid] = x[(size_t)(b0 + tid) * TT + s];
        __syncthreads();
        STEP(wi_r, wi_z, wi_n, c_r, c_z, bi_n, bh_n, hbuf + (s & 1) * HBUF_N);
        GBAR();
    }

    // switch to decoder weights/params
    #pragma unroll
    for (int g = 0; g < 3; ++g) {
        const size_t row = (size_t)(g * HD + ur) * HD;
        #pragma unroll
        for (int i = 0; i < 4; ++i)
            wW[g][i] = *(const float4*)&dWh[row + i * 128 + 4 * kq];
    }
    wi_r = dWi[ur]; wi_z = dWi[HD + ur]; wi_n = dWi[2 * HD + ur];
    c_r  = dbi[ur] + dbh[ur];
    c_z  = dbi[HD + ur] + dbh[HD + ur];
    bi_n = dbi[2 * HD + ur]; bh_n = dbh[2 * HD + ur];

    // ---------------- decoder ----------------
    for (int s = 0; s <= TT; ++s) {
        STAGE((s + 1) & 1);
        __syncthreads();
        // y[b=u] = hs[u] . linW + lb  (redundant per block, no extra barrier)
        {
            float p = 0.f;
            #pragma unroll
            for (int i = 0; i < 4; ++i) {
                const float4 hv = *(const float4*)&hs[u][4 * kq + 128 * i];
                const float4 lv = *(const float4*)&lin_s[4 * kq + 128 * i];
                p = fmaf(hv.x, lv.x, p); p = fmaf(hv.y, lv.y, p);
                p = fmaf(hv.z, lv.z, p); p = fmaf(hv.w, lv.w, p);
            }
            p += __shfl_xor(p, 1);  p += __shfl_xor(p, 2);  p += __shfl_xor(p, 4);
            p += __shfl_xor(p, 8);  p += __shfl_xor(p, 16);
            if (kq == 0) xin_s[u] = p + lb;
        }
        __syncthreads();
        if (s >= 1 && us == 0 && tid < NBB)
            out[(size_t)(b0 + tid) * TT + (TT - s)] = xin_s[tid];
        if (s < TT) {
            STEP(wi_r, wi_z, wi_n, c_r, c_z, bi_n, bh_n, hbuf + (s & 1) * HBUF_N);
            GBAR();
        }
    }
}

extern "C" void kernel_launch(void* const* d_in, const int* in_sizes, int n_in,
                              void* d_out, int out_size, void* d_ws, size_t ws_size,
                              hipStream_t stream) {
    const float* x    = (const float*)d_in[0];
    const float* eWi  = (const float*)d_in[1];
    const float* eWh  = (const float*)d_in[2];
    const float* ebi  = (const float*)d_in[3];
    const float* ebh  = (const float*)d_in[4];
    const float* dWi  = (const float*)d_in[5];
    const float* dWh  = (const float*)d_in[6];
    const float* dbi  = (const float*)d_in[7];
    const float* dbh  = (const float*)d_in[8];
    const float* linW = (const float*)d_in[9];
    const float* linb = (const float*)d_in[10];
    float* out  = (float*)d_out;

    float* hbuf   = (float*)d_ws;                 // 2 x 256 KB h double-buffer
    int*   sync_w = (int*)(hbuf + 2 * HBUF_N);    // 8 x 64 ints

    init_sync<<<1, NGRP * 64, 0, stream>>>(sync_w);
    gru_persist<<<dim3(NBLK), dim3(NTHR), 0, stream>>>(
        x, eWi, eWh, ebi, ebh, dWi, dWh, dbi, dbh, linW, linb,
        hbuf, sync_w, out);
}